// Round 14
// baseline (138.589 us; speedup 1.0000x reference)
//
#include <hip/hip_runtime.h>
#include <math.h>

#define VOCAB 30000
#define DMODEL 256
#define NHEAD 4
#define SEQ 1024
#define BATCH 16
#define MROWS (BATCH*SEQ)   // 16384
#define SL2 0.18033688011112042f            // 0.125 * log2(e)
#define NEG2 (-1.4426950408889634e10f)      // -1e10 * log2(e)

typedef __attribute__((ext_vector_type(8))) short bf16x8;
typedef __attribute__((ext_vector_type(4))) float f32x4;

#if __has_builtin(__builtin_amdgcn_exp2f)
#define EXP2F __builtin_amdgcn_exp2f
#else
#define EXP2F exp2f
#endif

__device__ __forceinline__ unsigned short f2b(float f) {
    unsigned int u = __float_as_uint(f);
    unsigned int r = (u + 0x7FFFu + ((u >> 16) & 1u)) >> 16;
    return (unsigned short)r;
}
__device__ __forceinline__ unsigned short f2b_trunc(float f) {
    return (unsigned short)(__float_as_uint(f) >> 16);
}
__device__ __forceinline__ float b2f(unsigned short s) {
    unsigned int u = ((unsigned int)s) << 16;
    return __uint_as_float(u);
}

// ---------------- merged prep: pe | span | qkv cvt | fc/ff cvt | vocab transpose ----------------
__global__ __launch_bounds__(256) void prep_kernel(const int* __restrict__ mask, int* __restrict__ spans,
                                                   float* __restrict__ pe,
                                                   const float* __restrict__ wq, const float* __restrict__ wk,
                                                   const float* __restrict__ wv, const float* __restrict__ bq,
                                                   const float* __restrict__ bk, const float* __restrict__ bv,
                                                   unsigned short* __restrict__ wqkv, float* __restrict__ bias768,
                                                   const float* __restrict__ fcw, const float* __restrict__ f1w,
                                                   const float* __restrict__ f2w, unsigned short* __restrict__ wb3,
                                                   const float* __restrict__ embW, const float* __restrict__ eb,
                                                   unsigned short* __restrict__ embT) {
    int blk = blockIdx.x;
    int t = threadIdx.x;
    if (blk < 64) {
        __shared__ double down[128];
        if (t < 128) down[t] = exp((double)(2 * t) * (-9.210340371976184 / 256.0));
        __syncthreads();
        int d2 = t & 127, half = t >> 7;
        #pragma unroll
        for (int i = 0; i < 8; i++) {
            int n = blk * 16 + half * 8 + i;
            double ang = (double)n * down[d2];
            pe[n * DMODEL + 2 * d2]     = (float)(sin(ang) * 0.1);
            pe[n * DMODEL + 2 * d2 + 1] = (float)(cos(ang) * 0.1);
        }
    } else if (blk < 80) {
        int b = blk - 64;
        __shared__ int smin, smax;
        if (t == 0) { smin = SEQ; smax = -1; }
        __syncthreads();
        int lmin = SEQ, lmax = -1;
        for (int i = t; i < SEQ; i += 256) {
            if (mask[b * SEQ + i] != 0) { lmin = min(lmin, i); lmax = max(lmax, i); }
        }
        atomicMin(&smin, lmin);
        atomicMax(&smax, lmax);
        __syncthreads();
        if (t == 0) {
            int st, en;
            if (smax < 0) { st = 0; en = SEQ - 1; }
            else          { st = smin; en = smax; }
            spans[b * 2] = st; spans[b * 2 + 1] = en;
        }
    } else if (blk < 849) {
        int cb = blk - 80;
        if (cb < 768) {
            const float* src = (cb < 256) ? wq : (cb < 512) ? wk : wv;
            wqkv[cb * 256 + t] = f2b(src[(cb & 255) * 256 + t]);
        } else {
            for (int j = t; j < 768; j += 256)
                bias768[j] = (j < 256) ? bq[j] : (j < 512) ? bk[j - 256] : bv[j - 512];
        }
    } else if (blk < 1617) {
        int cb = blk - 849;
        const float* src = (cb < 256) ? fcw : (cb < 512) ? f1w : f2w;
        wb3[cb * 256 + t] = f2b(src[(cb & 255) * 256 + t]);
    } else {
        __shared__ float tsh[32][33];
        int tb = blk - 1617;
        int bx = tb % 938, by = tb / 938;
        int tx = t & 31, ty = t >> 5;   // 32 x 8
        int c0 = bx * 32, r0 = by * 32;
        for (int i = 0; i < 32; i += 8) {
            int r = r0 + ty + i, c = c0 + tx;
            if (c < VOCAB) tsh[ty + i][tx] = embW[(size_t)r * VOCAB + c];
        }
        __syncthreads();
        float ebv = eb[r0 + tx];
        for (int i = 0; i < 32; i += 8) {
            int c = c0 + ty + i, r = r0 + tx;
            if (c < VOCAB) embT[(size_t)c * DMODEL + r] = f2b(tsh[tx][ty + i] + ebv);
        }
    }
}

// ---------------- fused embed + QKV GEMM: gather+pe in staging, x0b side-output ----------------
__global__ __launch_bounds__(512) void qkv_kernel(const int* __restrict__ ids,
                                                  const unsigned short* __restrict__ embT,
                                                  const float* __restrict__ pe,
                                                  const unsigned short* __restrict__ W,
                                                  const float* __restrict__ bias,
                                                  unsigned short* __restrict__ x0b,
                                                  unsigned short* __restrict__ Qb,
                                                  unsigned short* __restrict__ Kb,
                                                  unsigned short* __restrict__ Vt) {
    __shared__ unsigned short XA[4 * 64 * 64];   // 4 k-chunks of [64][128B], swizzled
    __shared__ unsigned short Bs[2][256 * 64];   // double-buffered
    int tid = threadIdx.x;
    int m0 = blockIdx.x * 64;
    int w = tid >> 6, l = tid & 63;
    int wrow = w >> 1, wcol = w & 1;
    int lg = l >> 4, ll = l & 15;
    int bb = m0 >> 10;

    // staging = embedding gather + pos-enc + bf16 convert; also writes x0b for residual
    #pragma unroll
    for (int i = 0; i < 4; i++) {
        int s = tid + i * 512;
        int row = s >> 5;                 // 0..63
        int kb = (s & 31) * 16;           // byte in 512B row
        int kt = kb >> 7, within = kb & 127;
        int swz = within ^ ((row & 7) << 4);
        int tok = m0 + row;
        int id = ids[tok];
        int n = tok & (SEQ - 1);
        bf16x8 ev = *(const bf16x8*)((const char*)embT + (size_t)id * 512 + kb);
        float4 p0 = *(const float4*)((const char*)pe + (size_t)n * 1024 + kb * 2);
        float4 p1 = *(const float4*)((const char*)pe + (size_t)n * 1024 + kb * 2 + 16);
        bf16x8 xv;
        xv[0] = (short)f2b(b2f((unsigned short)ev[0]) + p0.x);
        xv[1] = (short)f2b(b2f((unsigned short)ev[1]) + p0.y);
        xv[2] = (short)f2b(b2f((unsigned short)ev[2]) + p0.z);
        xv[3] = (short)f2b(b2f((unsigned short)ev[3]) + p0.w);
        xv[4] = (short)f2b(b2f((unsigned short)ev[4]) + p1.x);
        xv[5] = (short)f2b(b2f((unsigned short)ev[5]) + p1.y);
        xv[6] = (short)f2b(b2f((unsigned short)ev[6]) + p1.z);
        xv[7] = (short)f2b(b2f((unsigned short)ev[7]) + p1.w);
        *(bf16x8*)((char*)XA + kt * 8192 + row * 128 + swz) = xv;
        *(bf16x8*)((char*)x0b + (size_t)tok * 512 + kb) = xv;
    }

    for (int nb = 0; nb < 3; nb++) {
        f32x4 acc[8] = {};
        #pragma unroll
        for (int i = 0; i < 4; i++) {
            int s = tid + i * 512;
            int row = s >> 3, kb = (s & 7) * 16;
            int swz = kb ^ ((row & 7) << 4);
            float4 bv = *(const float4*)((const char*)W + (size_t)(nb * 256 + row) * 512 + kb);
            *(float4*)((char*)Bs[0] + row * 128 + swz) = bv;
        }
        __syncthreads();

        for (int kt = 0; kt < 4; kt++) {
            int cur = kt & 1;
            float4 pre[4];
            if (kt < 3) {
                #pragma unroll
                for (int i = 0; i < 4; i++) {
                    int s = tid + i * 512;
                    int row = s >> 3, kb = (s & 7) * 16;
                    pre[i] = *(const float4*)((const char*)W + (size_t)(nb * 256 + row) * 512 + (kt + 1) * 128 + kb);
                }
            }
            int arow = wrow * 16 + ll;
            bf16x8 af[2];
            #pragma unroll
            for (int ks = 0; ks < 2; ks++)
                af[ks] = *(const bf16x8*)((const char*)XA + kt * 8192 + arow * 128 + ((lg * 16 + ks * 64) ^ ((arow & 7) << 4)));
            #pragma unroll
            for (int nf = 0; nf < 8; nf++) {
                int brow = wcol * 128 + nf * 16 + ll;
                #pragma unroll
                for (int ks = 0; ks < 2; ks++) {
                    bf16x8 bf = *(const bf16x8*)((const char*)Bs[cur] + brow * 128 + ((lg * 16 + ks * 64) ^ ((brow & 7) << 4)));
                    acc[nf] = __builtin_amdgcn_mfma_f32_16x16x32_bf16(af[ks], bf, acc[nf], 0, 0, 0);
                }
            }
            if (kt < 3) {
                #pragma unroll
                for (int i = 0; i < 4; i++) {
                    int s = tid + i * 512;
                    int row = s >> 3, kb = (s & 7) * 16;
                    int swz = kb ^ ((row & 7) << 4);
                    *(float4*)((char*)Bs[cur ^ 1] + row * 128 + swz) = pre[i];
                }
            }
            __syncthreads();
        }
        // epilogue for this nb (0=Q,1=K,2=V)
        #pragma unroll
        for (int nf = 0; nf < 8; nf++) {
            int col = wcol * 128 + nf * 16 + ll;      // 0..255
            float bv = bias[nb * 256 + col];
            int hh = col >> 6, dk = col & 63;
            if (nb == 2) {
                unsigned int lo = (unsigned int)f2b(acc[nf][0] + bv) | ((unsigned int)f2b(acc[nf][1] + bv) << 16);
                unsigned int hi = (unsigned int)f2b(acc[nf][2] + bv) | ((unsigned int)f2b(acc[nf][3] + bv) << 16);
                int ns = (m0 & 1023) + wrow * 16 + lg * 4;
                unsigned int* dst = (unsigned int*)(Vt + ((((size_t)bb * 4 + hh) * 64) + dk) * 1024 + ns);
                dst[0] = lo;
                dst[1] = hi;
            } else {
                #pragma unroll
                for (int r2 = 0; r2 < 4; r2++) {
                    int ns = (m0 & 1023) + wrow * 16 + lg * 4 + r2;
                    float v = acc[nf][r2] + bv;
                    if (nb == 0)
                        Qb[((((size_t)bb * 4 + hh) * 1024) + ns) * 64 + dk] = f2b(v * SL2);
                    else
                        Kb[((((size_t)bb * 4 + hh) * 1024) + ns) * 64 + dk] = f2b(v);
                }
            }
        }
    }
}

// ---------------- cooperative flash attention, 8 waves x 16 q-rows, dbuf K/V, 1 barrier/iter ----------------
__global__ __launch_bounds__(512) void attn_coop(const unsigned short* __restrict__ Qb,
                                                 const unsigned short* __restrict__ Kb,
                                                 const unsigned short* __restrict__ Vt,
                                                 const int* __restrict__ spans,
                                                 unsigned short* __restrict__ attb) {
    __shared__ unsigned short Ks[2][64 * 64];
    __shared__ unsigned short Vs[2][64 * 64];
    __shared__ __align__(16) unsigned short Ps[8][16 * 72];
    int tid = threadIdx.x;
    int w = tid >> 6, l = tid & 63;
    int id = blockIdx.x;               // 0..511
    int c = id & 7, rest = id >> 3;
    int bh = c * 8 + (rest >> 3);
    int qg = rest & 7;
    int q0 = qg * 128 + w * 16;
    int b = bh >> 2, h = bh & 3;
    int lg = l >> 4, ll = l & 15;
    const char* Kp = (const char*)(Kb + (size_t)bh * SEQ * 64);
    const char* Vp = (const char*)(Vt + (size_t)bh * 64 * SEQ);
    const unsigned short* Qp = Qb + (size_t)bh * SEQ * 64;
    int start = spans[b * 2], end = spans[b * 2 + 1];

    bf16x8 qf[2];
    #pragma unroll
    for (int ks = 0; ks < 2; ks++)
        qf[ks] = *(const bf16x8*)(Qp + (size_t)(q0 + ll) * 64 + lg * 8 + ks * 32);

    bf16x8 ones;
    #pragma unroll
    for (int i = 0; i < 8; i++) ones[i] = (short)0x3F80;   // bf16 1.0

    f32x4 o[4] = {};
    f32x4 accl = {};
    bool rowok[4];
    #pragma unroll
    for (int r2 = 0; r2 < 4; r2++) {
        int rr = q0 + lg * 4 + r2;
        rowok[r2] = (rr >= start) && (rr < end);
    }

    int srow = tid >> 3, skb = (tid & 7) * 16;
    int sswz = skb ^ ((srow & 7) << 4);

    {
        float4 kv0v = *(const float4*)(Kp + (size_t)srow * 128 + skb);
        float4 vv0 = *(const float4*)(Vp + (size_t)srow * 2048 + skb);
        *(float4*)((char*)Ks[0] + srow * 128 + sswz) = kv0v;
        *(float4*)((char*)Vs[0] + srow * 128 + sswz) = vv0;
    }

    for (int ct = 0; ct < 16; ct++) {
        int cur = ct & 1;
        int kv0 = ct * 64;
        __syncthreads();

        float4 kreg, vreg;
        if (ct < 15) {
            int kvn = kv0 + 64;
            kreg = *(const float4*)(Kp + (size_t)(kvn + srow) * 128 + skb);
            vreg = *(const float4*)(Vp + (size_t)srow * 2048 + kvn * 2 + skb);
        }

        f32x4 s4[4];
        #pragma unroll
        for (int nf = 0; nf < 4; nf++) {
            int cc = kv0 + nf * 16 + ll;
            float ci = ((cc >= start) && (cc < end)) ? 0.f : NEG2;
            f32x4 cv = { ci, ci, ci, ci };
            s4[nf] = cv;
        }
        #pragma unroll
        for (int ks = 0; ks < 2; ks++)
            #pragma unroll
            for (int nf = 0; nf < 4; nf++) {
                int row = nf * 16 + ll;
                bf16x8 kf = *(const bf16x8*)((const char*)Ks[cur] + row * 128 + ((lg * 16 + ks * 64) ^ ((row & 7) << 4)));
                s4[nf] = __builtin_amdgcn_mfma_f32_16x16x32_bf16(qf[ks], kf, s4[nf], 0, 0, 0);
            }

        #pragma unroll
        for (int nf = 0; nf < 4; nf++)
            #pragma unroll
            for (int r2 = 0; r2 < 4; r2++) {
                float sv = rowok[r2] ? s4[nf][r2] : 0.f;
                s4[nf][r2] = EXP2F(sv);
            }

        #pragma unroll
        for (int nf = 0; nf < 4; nf++)
            #pragma unroll
            for (int r2 = 0; r2 < 4; r2++)
                Ps[w][(lg * 4 + r2) * 72 + nf * 16 + ll] = f2b_trunc(s4[nf][r2]);

        bf16x8 pa[2];
        #pragma unroll
        for (int ks = 0; ks < 2; ks++)
            pa[ks] = *(const bf16x8*)(&Ps[w][ll * 72 + lg * 8 + ks * 32]);

        #pragma unroll
        for (int ks = 0; ks < 2; ks++)
            #pragma unroll
            for (int cf = 0; cf < 4; cf++) {
                int row = cf * 16 + ll;
                bf16x8 vf = *(const bf16x8*)((const char*)Vs[cur] + row * 128 + ((lg * 16 + ks * 64) ^ ((row & 7) << 4)));
                o[cf] = __builtin_amdgcn_mfma_f32_16x16x32_bf16(pa[ks], vf, o[cf], 0, 0, 0);
            }
        #pragma unroll
        for (int ks = 0; ks < 2; ks++)
            accl = __builtin_amdgcn_mfma_f32_16x16x32_bf16(pa[ks], ones, accl, 0, 0, 0);

        if (ct < 15) {
            *(float4*)((char*)Ks[cur ^ 1] + srow * 128 + sswz) = kreg;
            *(float4*)((char*)Vs[cur ^ 1] + srow * 128 + sswz) = vreg;
        }
    }

    #pragma unroll
    for (int r2 = 0; r2 < 4; r2++) {
        float inv = 1.f / accl[r2];
        int row = q0 + lg * 4 + r2;
        #pragma unroll
        for (int cf = 0; cf < 4; cf++) {
            int dk = cf * 16 + ll;
            attb[((size_t)b * SEQ + row) * 256 + h * 64 + dk] = f2b(o[cf][r2] * inv);
        }
    }
}

// ---------------- fused FFN chain: 512 blocks x 32 rows, single-buffer Bs, 2 blocks/CU ----------------
__global__ __launch_bounds__(512) void ffn_kernel(const unsigned short* __restrict__ attb,
                                                  const unsigned short* __restrict__ x0b,
                                                  const unsigned short* __restrict__ W3,
                                                  const float* __restrict__ fcb,
                                                  const float* __restrict__ f1b,
                                                  const float* __restrict__ f2bv,
                                                  float* __restrict__ part) {
    __shared__ unsigned short BufA[4 * 32 * 64];   // attb staged -> later h (16KB)
    __shared__ unsigned short BufB[4 * 32 * 64];   // x1 (16KB)
    __shared__ unsigned short Bs[256 * 64];        // 32KB, single buffer
    int tid = threadIdx.x;
    int m0 = blockIdx.x * 32;
    int w = tid >> 6, l = tid & 63;
    int wrow = w >> 2, wcol = w & 3;               // 2 x 4
    int lg = l >> 4, ll = l & 15;
    int arow = wrow * 16 + ll;                     // 0..31

    // stage attb -> BufA (32 rows x 512B = 16KB; 2 float4/thread)
    #pragma unroll
    for (int i = 0; i < 2; i++) {
        int s = tid + i * 512;
        int row = s >> 5;              // 0..31
        int kb = (s & 31) * 16;
        int kt = kb >> 7, within = kb & 127;
        int swz = within ^ ((row & 7) << 4);
        float4 av = *(const float4*)((const char*)attb + (size_t)(m0 + row) * 512 + kb);
        *(float4*)((char*)BufA + kt * 4096 + row * 128 + swz) = av;
    }

    #pragma unroll
    for (int phase = 0; phase < 3; phase++) {
        const unsigned short* Wp = W3 + phase * 65536;
        const char* Asrc = (phase == 1) ? (const char*)BufB : (const char*)BufA;
        f32x4 acc[4] = {};

        for (int kt = 0; kt < 4; kt++) {
            float4 pre[4];
            #pragma unroll
            for (int i = 0; i < 4; i++) {
                int s = tid + i * 512;
                int row = s >> 3, kb = (s & 7) * 16;
                pre[i] = *(const float4*)((const char*)Wp + (size_t)row * 512 + kt * 128 + kb);
            }
            __syncthreads();   // everyone done reading Bs (prev kt)
            #pragma unroll
            for (int i = 0; i < 4; i++) {
                int s = tid + i * 512;
                int row = s >> 3, kb = (s & 7) * 16;
                int swz = kb ^ ((row & 7) << 4);
                *(float4*)((char*)Bs + row * 128 + swz) = pre[i];
            }
            __syncthreads();   // Bs ready
            bf16x8 af[2];
            #pragma unroll
            for (int ks = 0; ks < 2; ks++)
                af[ks] = *(const bf16x8*)(Asrc + kt * 4096 + arow * 128 + ((lg * 16 + ks * 64) ^ ((arow & 7) << 4)));
            #pragma unroll
            for (int nf = 0; nf < 4; nf++) {
                int brow = wcol * 64 + nf * 16 + ll;
                #pragma unroll
                for (int ks = 0; ks < 2; ks++) {
                    bf16x8 bf = *(const bf16x8*)((const char*)Bs + brow * 128 + ((lg * 16 + ks * 64) ^ ((brow & 7) << 4)));
                    acc[nf] = __builtin_amdgcn_mfma_f32_16x16x32_bf16(af[ks], bf, acc[nf], 0, 0, 0);
                }
            }
        }

        if (phase == 0) {
            __syncthreads();  // compute done before BufB writes
            #pragma unroll
            for (int nf = 0; nf < 4; nf++) {
                int col = wcol * 64 + nf * 16 + ll;
                float bv = fcb[col];
                int kt = col >> 6;
                int byteoff = (2 * (col & 63));
                #pragma unroll
                for (int r2 = 0; r2 < 4; r2++) {
                    int row = wrow * 16 + lg * 4 + r2;
                    *(unsigned short*)((char*)BufB + kt * 4096 + row * 128 + (byteoff ^ ((row & 7) << 4))) = f2b(acc[nf][r2] + bv);
                }
            }
            __syncthreads();
            // residual: BufB += x0b
            #pragma unroll
            for (int i = 0; i < 2; i++) {
                int s = tid + i * 512;
                int row = s >> 5;
                int kb = (s & 31) * 16;
                int kt = kb >> 7, within = kb & 127;
                int swz = within ^ ((row & 7) << 4);
                bf16x8* dst = (bf16x8*)((char*)BufB + kt * 4096 + row * 128 + swz);
                bf16x8 xv = *dst;
                bf16x8 rv = *(const bf16x8*)((const char*)x0b + (size_t)(m0 + row) * 512 + kb);
                bf16x8 res;
                #pragma unroll
                for (int jj = 0; jj < 8; jj++)
                    res[jj] = (short)f2b(b2f((unsigned short)xv[jj]) + b2f((unsigned short)rv[jj]));
                *dst = res;
            }
        } else if (phase == 1) {
            __syncthreads();  // compute done before BufA overwrite
            #pragma unroll
            for (int nf = 0; nf < 4; nf++) {
                int col = wcol * 64 + nf * 16 + ll;
                float bv = f1b[col];
                int kt = col >> 6;
                int byteoff = (2 * (col & 63));
                #pragma unroll
                for (int r2 = 0; r2 < 4; r2++) {
                    int row = wrow * 16 + lg * 4 + r2;
                    float v = acc[nf][r2] + bv;
                    v = 0.5f * v * (1.f + erff(v * 0.70710678118654752f));
                    *(unsigned short*)((char*)BufA + kt * 4096 + row * 128 + (byteoff ^ ((row & 7) << 4))) = f2b(v);
                }
            }
        } else {
            int bb = m0 >> 10;
            int chunk = ((m0 & 1023) >> 5) * 2 + wrow;   // 0..63 per batch
            #pragma unroll
            for (int nf = 0; nf < 4; nf++) {
                int col = wcol * 64 + nf * 16 + ll;
                float s_ = acc[nf][0] + acc[nf][1] + acc[nf][2] + acc[nf][3];
                s_ += __shfl_xor(s_, 16);
                s_ += __shfl_xor(s_, 32);
                s_ += 16.f * f2bv[col];
                if (lg == 0)
                    part[((size_t)bb * 64 + chunk) * 256 + col] = s_;
            }
        }
    }
}

// ---------------- fused pool stage 2 + MLP head (eval BatchNorm) ----------------
__global__ __launch_bounds__(128) void head2_kernel(const float* __restrict__ part,
                                                    const float* __restrict__ h1_w, const float* __restrict__ h1_b,
                                                    const float* __restrict__ g, const float* __restrict__ be,
                                                    const float* __restrict__ mu, const float* __restrict__ var,
                                                    const float* __restrict__ h2_w, const float* __restrict__ h2_b,
                                                    float* __restrict__ out) {
    int b = blockIdx.x, j = threadIdx.x;
    __shared__ float pl[256];
    __shared__ float red[128];
    float s0 = 0.f, s1 = 0.f;
    for (int ch = 0; ch < 64; ch++) {
        s0 += part[((size_t)b * 64 + ch) * 256 + j];
        s1 += part[((size_t)b * 64 + ch) * 256 + j + 128];
    }
    pl[j] = s0 * (1.f / 1024.f);
    pl[j + 128] = s1 * (1.f / 1024.f);
    __syncthreads();
    float s = 0.f;
    for (int d = 0; d < 256; d++) s = fmaf(pl[d], h1_w[j * 256 + d], s);
    s += h1_b[j];
    s = (s - mu[j]) / sqrtf(var[j] + 1e-5f) * g[j] + be[j];
    s = fmaxf(s, 0.f);
    red[j] = s * h2_w[j];
    __syncthreads();
    for (int off = 64; off; off >>= 1) {
        if (j < off) red[j] += red[j + off];
        __syncthreads();
    }
    if (j == 0) out[b] = red[0] + h2_b[0];
}

// ---------------- launch ----------------
extern "C" void kernel_launch(void* const* d_in, const int* in_sizes, int n_in,
                              void* d_out, int out_size, void* d_ws, size_t ws_size,
                              hipStream_t stream) {
    (void)in_sizes; (void)n_in; (void)out_size; (void)ws_size;
    const int*   ids    = (const int*)d_in[0];
    const int*   amask  = (const int*)d_in[1];
    const float* emb_W  = (const float*)d_in[2];
    const float* emb_b  = (const float*)d_in[3];
    const float* wq = (const float*)d_in[4],  *bq = (const float*)d_in[5];
    const float* wk = (const float*)d_in[6],  *bk = (const float*)d_in[7];
    const float* wv = (const float*)d_in[8],  *bv = (const float*)d_in[9];
    const float* fcw = (const float*)d_in[10], *fcb = (const float*)d_in[11];
    const float* f1w = (const float*)d_in[12], *f1b = (const float*)d_in[13];
    const float* f2w = (const float*)d_in[14], *f2b_ = (const float*)d_in[15];
    const float* h1w = (const float*)d_in[16], *h1b = (const float*)d_in[17];
    const float* bng = (const float*)d_in[18], *bnb = (const float*)d_in[19];
    const float* bnm = (const float*)d_in[20], *bnv = (const float*)d_in[21];
    const float* h2w = (const float*)d_in[22], *h2b = (const float*)d_in[23];
    float* out = (float*)d_out;
    float* ws = (float*)d_ws;

    // workspace layout (float units)
    const size_t O_PE   = 0;                        // 262,144
    const size_t O_EMBT = O_PE + 262144;            // 3,840,000 (bf16 30000x256)
    const size_t O_X0B  = O_EMBT + 3840000;         // 2,097,152
    const size_t O_Q    = O_X0B + 2097152;          // 2,097,152
    const size_t O_K    = O_Q + 2097152;            // 2,097,152
    const size_t O_V    = O_K + 2097152;            // 2,097,152
    const size_t O_ATT  = O_V + 2097152;            // 2,097,152
    const size_t O_WQKV = O_ATT + 2097152;          // 98,304 (768x256 shorts)
    const size_t O_WB3  = O_WQKV + 98304;           // 98,304
    const size_t O_B768 = O_WB3 + 98304;            // 768
    const size_t O_PART = O_B768 + 768;             // 262,144 (16x64x256 f32)
    const size_t O_SPAN = O_PART + 262144;

    float* pe   = ws + O_PE;
    unsigned short* embT = (unsigned short*)(ws + O_EMBT);
    unsigned short* x0b  = (unsigned short*)(ws + O_X0B);
    unsigned short* Qb   = (unsigned short*)(ws + O_Q);
    unsigned short* Kb   = (unsigned short*)(ws + O_K);
    unsigned short* Vt   = (unsigned short*)(ws + O_V);
    unsigned short* attb = (unsigned short*)(ws + O_ATT);
    unsigned short* wqkv = (unsigned short*)(ws + O_WQKV);
    unsigned short* wb3  = (unsigned short*)(ws + O_WB3);
    float* bias768 = ws + O_B768;
    float* part = ws + O_PART;
    int* spans  = (int*)(ws + O_SPAN);

    prep_kernel<<<1617 + 938 * 8, 256, 0, stream>>>(amask, spans, pe,
                                                    wq, wk, wv, bq, bk, bv, wqkv, bias768,
                                                    fcw, f1w, f2w, wb3,
                                                    emb_W, emb_b, embT);

    qkv_kernel<<<256, 512, 0, stream>>>(ids, embT, pe, wqkv, bias768, x0b, Qb, Kb, Vt);

    attn_coop<<<512, 512, 0, stream>>>(Qb, Kb, Vt, spans, attb);

    ffn_kernel<<<512, 512, 0, stream>>>(attb, x0b, wb3, fcb, f1b, f2b_, part);

    head2_kernel<<<BATCH, 128, 0, stream>>>(part, h1w, h1b, bng, bnb, bnm, bnv, h2w, h2b, out);
}

// Round 15
// 92.557 us; speedup vs baseline: 1.4973x; 1.4973x over previous
//
#include <hip/hip_runtime.h>
#include <math.h>

#define VOCAB 30000
#define DMODEL 256
#define NHEAD 4
#define SEQ 1024
#define BATCH 16
#define MROWS (BATCH*SEQ)   // 16384
#define SL2 0.18033688011112042f            // 0.125 * log2(e)
#define NEG2 (-1.4426950408889634e10f)      // -1e10 * log2(e)

typedef __attribute__((ext_vector_type(8))) short bf16x8;
typedef __attribute__((ext_vector_type(4))) float f32x4;

#if __has_builtin(__builtin_amdgcn_exp2f)
#define EXP2F __builtin_amdgcn_exp2f
#else
#define EXP2F exp2f
#endif

__device__ __forceinline__ unsigned short f2b(float f) {
    unsigned int u = __float_as_uint(f);
    unsigned int r = (u + 0x7FFFu + ((u >> 16) & 1u)) >> 16;
    return (unsigned short)r;
}
__device__ __forceinline__ unsigned short f2b_trunc(float f) {
    return (unsigned short)(__float_as_uint(f) >> 16);
}
__device__ __forceinline__ float b2f(unsigned short s) {
    unsigned int u = ((unsigned int)s) << 16;
    return __uint_as_float(u);
}

// ---------------- merged prep: pe | span | qkv cvt | fc/ff cvt | vocab transpose ----------------
__global__ __launch_bounds__(256) void prep_kernel(const int* __restrict__ mask, int* __restrict__ spans,
                                                   float* __restrict__ pe,
                                                   const float* __restrict__ wq, const float* __restrict__ wk,
                                                   const float* __restrict__ wv, const float* __restrict__ bq,
                                                   const float* __restrict__ bk, const float* __restrict__ bv,
                                                   unsigned short* __restrict__ wqkv, float* __restrict__ bias768,
                                                   const float* __restrict__ fcw, const float* __restrict__ f1w,
                                                   const float* __restrict__ f2w, unsigned short* __restrict__ wb3,
                                                   const float* __restrict__ embW, const float* __restrict__ eb,
                                                   unsigned short* __restrict__ embT) {
    int blk = blockIdx.x;
    int t = threadIdx.x;
    if (blk < 64) {
        __shared__ double down[128];
        if (t < 128) down[t] = exp((double)(2 * t) * (-9.210340371976184 / 256.0));
        __syncthreads();
        int d2 = t & 127, half = t >> 7;
        #pragma unroll
        for (int i = 0; i < 8; i++) {
            int n = blk * 16 + half * 8 + i;
            double ang = (double)n * down[d2];
            pe[n * DMODEL + 2 * d2]     = (float)(sin(ang) * 0.1);
            pe[n * DMODEL + 2 * d2 + 1] = (float)(cos(ang) * 0.1);
        }
    } else if (blk < 80) {
        int b = blk - 64;
        __shared__ int smin, smax;
        if (t == 0) { smin = SEQ; smax = -1; }
        __syncthreads();
        int lmin = SEQ, lmax = -1;
        for (int i = t; i < SEQ; i += 256) {
            if (mask[b * SEQ + i] != 0) { lmin = min(lmin, i); lmax = max(lmax, i); }
        }
        atomicMin(&smin, lmin);
        atomicMax(&smax, lmax);
        __syncthreads();
        if (t == 0) {
            int st, en;
            if (smax < 0) { st = 0; en = SEQ - 1; }
            else          { st = smin; en = smax; }
            spans[b * 2] = st; spans[b * 2 + 1] = en;
        }
    } else if (blk < 849) {
        int cb = blk - 80;
        if (cb < 768) {
            const float* src = (cb < 256) ? wq : (cb < 512) ? wk : wv;
            wqkv[cb * 256 + t] = f2b(src[(cb & 255) * 256 + t]);
        } else {
            for (int j = t; j < 768; j += 256)
                bias768[j] = (j < 256) ? bq[j] : (j < 512) ? bk[j - 256] : bv[j - 512];
        }
    } else if (blk < 1617) {
        int cb = blk - 849;
        const float* src = (cb < 256) ? fcw : (cb < 512) ? f1w : f2w;
        wb3[cb * 256 + t] = f2b(src[(cb & 255) * 256 + t]);
    } else {
        __shared__ float tsh[32][33];
        int tb = blk - 1617;
        int bx = tb % 938, by = tb / 938;
        int tx = t & 31, ty = t >> 5;   // 32 x 8
        int c0 = bx * 32, r0 = by * 32;
        for (int i = 0; i < 32; i += 8) {
            int r = r0 + ty + i, c = c0 + tx;
            if (c < VOCAB) tsh[ty + i][tx] = embW[(size_t)r * VOCAB + c];
        }
        __syncthreads();
        float ebv = eb[r0 + tx];
        for (int i = 0; i < 32; i += 8) {
            int c = c0 + ty + i, r = r0 + tx;
            if (c < VOCAB) embT[(size_t)c * DMODEL + r] = f2b(tsh[tx][ty + i] + ebv);
        }
    }
}

// ---------------- fused embed + QKV GEMM: gather+pe in staging, x0b side-output ----------------
__global__ __launch_bounds__(512) void qkv_kernel(const int* __restrict__ ids,
                                                  const unsigned short* __restrict__ embT,
                                                  const float* __restrict__ pe,
                                                  const unsigned short* __restrict__ W,
                                                  const float* __restrict__ bias,
                                                  unsigned short* __restrict__ x0b,
                                                  unsigned short* __restrict__ Qb,
                                                  unsigned short* __restrict__ Kb,
                                                  unsigned short* __restrict__ Vt) {
    __shared__ unsigned short XA[4 * 64 * 64];   // 4 k-chunks of [64][128B], swizzled
    __shared__ unsigned short Bs[2][256 * 64];   // double-buffered
    int tid = threadIdx.x;
    int m0 = blockIdx.x * 64;
    int w = tid >> 6, l = tid & 63;
    int wrow = w >> 1, wcol = w & 1;
    int lg = l >> 4, ll = l & 15;
    int bb = m0 >> 10;

    // staging = embedding gather + pos-enc + bf16 convert; also writes x0b for residual
    #pragma unroll
    for (int i = 0; i < 4; i++) {
        int s = tid + i * 512;
        int row = s >> 5;                 // 0..63
        int kb = (s & 31) * 16;           // byte in 512B row
        int kt = kb >> 7, within = kb & 127;
        int swz = within ^ ((row & 7) << 4);
        int tok = m0 + row;
        int id = ids[tok];
        int n = tok & (SEQ - 1);
        bf16x8 ev = *(const bf16x8*)((const char*)embT + (size_t)id * 512 + kb);
        float4 p0 = *(const float4*)((const char*)pe + (size_t)n * 1024 + kb * 2);
        float4 p1 = *(const float4*)((const char*)pe + (size_t)n * 1024 + kb * 2 + 16);
        bf16x8 xv;
        xv[0] = (short)f2b(b2f((unsigned short)ev[0]) + p0.x);
        xv[1] = (short)f2b(b2f((unsigned short)ev[1]) + p0.y);
        xv[2] = (short)f2b(b2f((unsigned short)ev[2]) + p0.z);
        xv[3] = (short)f2b(b2f((unsigned short)ev[3]) + p0.w);
        xv[4] = (short)f2b(b2f((unsigned short)ev[4]) + p1.x);
        xv[5] = (short)f2b(b2f((unsigned short)ev[5]) + p1.y);
        xv[6] = (short)f2b(b2f((unsigned short)ev[6]) + p1.z);
        xv[7] = (short)f2b(b2f((unsigned short)ev[7]) + p1.w);
        *(bf16x8*)((char*)XA + kt * 8192 + row * 128 + swz) = xv;
        *(bf16x8*)((char*)x0b + (size_t)tok * 512 + kb) = xv;
    }

    for (int nb = 0; nb < 3; nb++) {
        f32x4 acc[8] = {};
        #pragma unroll
        for (int i = 0; i < 4; i++) {
            int s = tid + i * 512;
            int row = s >> 3, kb = (s & 7) * 16;
            int swz = kb ^ ((row & 7) << 4);
            float4 bv = *(const float4*)((const char*)W + (size_t)(nb * 256 + row) * 512 + kb);
            *(float4*)((char*)Bs[0] + row * 128 + swz) = bv;
        }
        __syncthreads();

        for (int kt = 0; kt < 4; kt++) {
            int cur = kt & 1;
            float4 pre[4];
            if (kt < 3) {
                #pragma unroll
                for (int i = 0; i < 4; i++) {
                    int s = tid + i * 512;
                    int row = s >> 3, kb = (s & 7) * 16;
                    pre[i] = *(const float4*)((const char*)W + (size_t)(nb * 256 + row) * 512 + (kt + 1) * 128 + kb);
                }
            }
            int arow = wrow * 16 + ll;
            bf16x8 af[2];
            #pragma unroll
            for (int ks = 0; ks < 2; ks++)
                af[ks] = *(const bf16x8*)((const char*)XA + kt * 8192 + arow * 128 + ((lg * 16 + ks * 64) ^ ((arow & 7) << 4)));
            #pragma unroll
            for (int nf = 0; nf < 8; nf++) {
                int brow = wcol * 128 + nf * 16 + ll;
                #pragma unroll
                for (int ks = 0; ks < 2; ks++) {
                    bf16x8 bf = *(const bf16x8*)((const char*)Bs[cur] + brow * 128 + ((lg * 16 + ks * 64) ^ ((brow & 7) << 4)));
                    acc[nf] = __builtin_amdgcn_mfma_f32_16x16x32_bf16(af[ks], bf, acc[nf], 0, 0, 0);
                }
            }
            if (kt < 3) {
                #pragma unroll
                for (int i = 0; i < 4; i++) {
                    int s = tid + i * 512;
                    int row = s >> 3, kb = (s & 7) * 16;
                    int swz = kb ^ ((row & 7) << 4);
                    *(float4*)((char*)Bs[cur ^ 1] + row * 128 + swz) = pre[i];
                }
            }
            __syncthreads();
        }
        // epilogue for this nb (0=Q,1=K,2=V)
        #pragma unroll
        for (int nf = 0; nf < 8; nf++) {
            int col = wcol * 128 + nf * 16 + ll;      // 0..255
            float bv = bias[nb * 256 + col];
            int hh = col >> 6, dk = col & 63;
            if (nb == 2) {
                unsigned int lo = (unsigned int)f2b(acc[nf][0] + bv) | ((unsigned int)f2b(acc[nf][1] + bv) << 16);
                unsigned int hi = (unsigned int)f2b(acc[nf][2] + bv) | ((unsigned int)f2b(acc[nf][3] + bv) << 16);
                int ns = (m0 & 1023) + wrow * 16 + lg * 4;
                unsigned int* dst = (unsigned int*)(Vt + ((((size_t)bb * 4 + hh) * 64) + dk) * 1024 + ns);
                dst[0] = lo;
                dst[1] = hi;
            } else {
                #pragma unroll
                for (int r2 = 0; r2 < 4; r2++) {
                    int ns = (m0 & 1023) + wrow * 16 + lg * 4 + r2;
                    float v = acc[nf][r2] + bv;
                    if (nb == 0)
                        Qb[((((size_t)bb * 4 + hh) * 1024) + ns) * 64 + dk] = f2b(v * SL2);
                    else
                        Kb[((((size_t)bb * 4 + hh) * 1024) + ns) * 64 + dk] = f2b(v);
                }
            }
        }
    }
}

// ---------------- cooperative flash attention, 8 waves x 16 q-rows, dbuf K/V, 1 barrier/iter ----------------
__global__ __launch_bounds__(512) void attn_coop(const unsigned short* __restrict__ Qb,
                                                 const unsigned short* __restrict__ Kb,
                                                 const unsigned short* __restrict__ Vt,
                                                 const int* __restrict__ spans,
                                                 unsigned short* __restrict__ attb) {
    __shared__ unsigned short Ks[2][64 * 64];
    __shared__ unsigned short Vs[2][64 * 64];
    __shared__ __align__(16) unsigned short Ps[8][16 * 72];
    int tid = threadIdx.x;
    int w = tid >> 6, l = tid & 63;
    int id = blockIdx.x;               // 0..511
    int c = id & 7, rest = id >> 3;
    int bh = c * 8 + (rest >> 3);
    int qg = rest & 7;
    int q0 = qg * 128 + w * 16;
    int b = bh >> 2, h = bh & 3;
    int lg = l >> 4, ll = l & 15;
    const char* Kp = (const char*)(Kb + (size_t)bh * SEQ * 64);
    const char* Vp = (const char*)(Vt + (size_t)bh * 64 * SEQ);
    const unsigned short* Qp = Qb + (size_t)bh * SEQ * 64;
    int start = spans[b * 2], end = spans[b * 2 + 1];

    bf16x8 qf[2];
    #pragma unroll
    for (int ks = 0; ks < 2; ks++)
        qf[ks] = *(const bf16x8*)(Qp + (size_t)(q0 + ll) * 64 + lg * 8 + ks * 32);

    bf16x8 ones;
    #pragma unroll
    for (int i = 0; i < 8; i++) ones[i] = (short)0x3F80;   // bf16 1.0

    f32x4 o[4] = {};
    f32x4 accl = {};
    bool rowok[4];
    #pragma unroll
    for (int r2 = 0; r2 < 4; r2++) {
        int rr = q0 + lg * 4 + r2;
        rowok[r2] = (rr >= start) && (rr < end);
    }

    int srow = tid >> 3, skb = (tid & 7) * 16;
    int sswz = skb ^ ((srow & 7) << 4);

    {
        float4 kv0v = *(const float4*)(Kp + (size_t)srow * 128 + skb);
        float4 vv0 = *(const float4*)(Vp + (size_t)srow * 2048 + skb);
        *(float4*)((char*)Ks[0] + srow * 128 + sswz) = kv0v;
        *(float4*)((char*)Vs[0] + srow * 128 + sswz) = vv0;
    }

    for (int ct = 0; ct < 16; ct++) {
        int cur = ct & 1;
        int kv0 = ct * 64;
        __syncthreads();

        float4 kreg, vreg;
        if (ct < 15) {
            int kvn = kv0 + 64;
            kreg = *(const float4*)(Kp + (size_t)(kvn + srow) * 128 + skb);
            vreg = *(const float4*)(Vp + (size_t)srow * 2048 + kvn * 2 + skb);
        }

        f32x4 s4[4];
        #pragma unroll
        for (int nf = 0; nf < 4; nf++) {
            int cc = kv0 + nf * 16 + ll;
            float ci = ((cc >= start) && (cc < end)) ? 0.f : NEG2;
            f32x4 cv = { ci, ci, ci, ci };
            s4[nf] = cv;
        }
        #pragma unroll
        for (int ks = 0; ks < 2; ks++)
            #pragma unroll
            for (int nf = 0; nf < 4; nf++) {
                int row = nf * 16 + ll;
                bf16x8 kf = *(const bf16x8*)((const char*)Ks[cur] + row * 128 + ((lg * 16 + ks * 64) ^ ((row & 7) << 4)));
                s4[nf] = __builtin_amdgcn_mfma_f32_16x16x32_bf16(qf[ks], kf, s4[nf], 0, 0, 0);
            }

        #pragma unroll
        for (int nf = 0; nf < 4; nf++)
            #pragma unroll
            for (int r2 = 0; r2 < 4; r2++) {
                float sv = rowok[r2] ? s4[nf][r2] : 0.f;
                s4[nf][r2] = EXP2F(sv);
            }

        #pragma unroll
        for (int nf = 0; nf < 4; nf++)
            #pragma unroll
            for (int r2 = 0; r2 < 4; r2++)
                Ps[w][(lg * 4 + r2) * 72 + nf * 16 + ll] = f2b_trunc(s4[nf][r2]);

        bf16x8 pa[2];
        #pragma unroll
        for (int ks = 0; ks < 2; ks++)
            pa[ks] = *(const bf16x8*)(&Ps[w][ll * 72 + lg * 8 + ks * 32]);

        #pragma unroll
        for (int ks = 0; ks < 2; ks++)
            #pragma unroll
            for (int cf = 0; cf < 4; cf++) {
                int row = cf * 16 + ll;
                bf16x8 vf = *(const bf16x8*)((const char*)Vs[cur] + row * 128 + ((lg * 16 + ks * 64) ^ ((row & 7) << 4)));
                o[cf] = __builtin_amdgcn_mfma_f32_16x16x32_bf16(pa[ks], vf, o[cf], 0, 0, 0);
            }
        #pragma unroll
        for (int ks = 0; ks < 2; ks++)
            accl = __builtin_amdgcn_mfma_f32_16x16x32_bf16(pa[ks], ones, accl, 0, 0, 0);

        if (ct < 15) {
            *(float4*)((char*)Ks[cur ^ 1] + srow * 128 + sswz) = kreg;
            *(float4*)((char*)Vs[cur ^ 1] + srow * 128 + sswz) = vreg;
        }
    }

    #pragma unroll
    for (int r2 = 0; r2 < 4; r2++) {
        float inv = 1.f / accl[r2];
        int row = q0 + lg * 4 + r2;
        #pragma unroll
        for (int cf = 0; cf < 4; cf++) {
            int dk = cf * 16 + ll;
            attb[((size_t)b * SEQ + row) * 256 + h * 64 + dk] = f2b(o[cf][r2] * inv);
        }
    }
}

// ---------------- fused FFN chain (r13 version: 256 blocks x 64 rows, dbuf Bs) ----------------
__global__ __launch_bounds__(512) void ffn_kernel(const unsigned short* __restrict__ attb,
                                                  const unsigned short* __restrict__ x0b,
                                                  const unsigned short* __restrict__ W3,
                                                  const float* __restrict__ fcb,
                                                  const float* __restrict__ f1b,
                                                  const float* __restrict__ f2bv,
                                                  float* __restrict__ part) {
    __shared__ unsigned short BufA[4 * 64 * 64];   // attb staged -> later h
    __shared__ unsigned short BufB[4 * 64 * 64];   // x1
    __shared__ unsigned short Bs[2][256 * 64];
    int tid = threadIdx.x;
    int m0 = blockIdx.x * 64;
    int w = tid >> 6, l = tid & 63;
    int wrow = w >> 1, wcol = w & 1;
    int lg = l >> 4, ll = l & 15;
    int arow = wrow * 16 + ll;

    // stage attb -> BufA
    #pragma unroll
    for (int i = 0; i < 4; i++) {
        int s = tid + i * 512;
        int row = s >> 5;
        int kb = (s & 31) * 16;
        int kt = kb >> 7, within = kb & 127;
        int swz = within ^ ((row & 7) << 4);
        float4 av = *(const float4*)((const char*)attb + (size_t)(m0 + row) * 512 + kb);
        *(float4*)((char*)BufA + kt * 8192 + row * 128 + swz) = av;
    }

    #pragma unroll
    for (int phase = 0; phase < 3; phase++) {
        const unsigned short* Wp = W3 + phase * 65536;
        const char* Asrc = (phase == 1) ? (const char*)BufB : (const char*)BufA;
        f32x4 acc[8] = {};
        // prologue: stage kt=0 into Bs[0]
        #pragma unroll
        for (int i = 0; i < 4; i++) {
            int s = tid + i * 512;
            int row = s >> 3, kb = (s & 7) * 16;
            int swz = kb ^ ((row & 7) << 4);
            float4 bv = *(const float4*)((const char*)Wp + (size_t)row * 512 + kb);
            *(float4*)((char*)Bs[0] + row * 128 + swz) = bv;
        }
        __syncthreads();

        for (int kt = 0; kt < 4; kt++) {
            int cur = kt & 1;
            float4 pre[4];
            if (kt < 3) {
                #pragma unroll
                for (int i = 0; i < 4; i++) {
                    int s = tid + i * 512;
                    int row = s >> 3, kb = (s & 7) * 16;
                    pre[i] = *(const float4*)((const char*)Wp + (size_t)row * 512 + (kt + 1) * 128 + kb);
                }
            }
            bf16x8 af[2];
            #pragma unroll
            for (int ks = 0; ks < 2; ks++)
                af[ks] = *(const bf16x8*)(Asrc + kt * 8192 + arow * 128 + ((lg * 16 + ks * 64) ^ ((arow & 7) << 4)));
            #pragma unroll
            for (int nf = 0; nf < 8; nf++) {
                int brow = wcol * 128 + nf * 16 + ll;
                #pragma unroll
                for (int ks = 0; ks < 2; ks++) {
                    bf16x8 bf = *(const bf16x8*)((const char*)Bs[cur] + brow * 128 + ((lg * 16 + ks * 64) ^ ((brow & 7) << 4)));
                    acc[nf] = __builtin_amdgcn_mfma_f32_16x16x32_bf16(af[ks], bf, acc[nf], 0, 0, 0);
                }
            }
            if (kt < 3) {
                #pragma unroll
                for (int i = 0; i < 4; i++) {
                    int s = tid + i * 512;
                    int row = s >> 3, kb = (s & 7) * 16;
                    int swz = kb ^ ((row & 7) << 4);
                    *(float4*)((char*)Bs[cur ^ 1] + row * 128 + swz) = pre[i];
                }
            }
            __syncthreads();
        }

        if (phase == 0) {
            #pragma unroll
            for (int nf = 0; nf < 8; nf++) {
                int col = wcol * 128 + nf * 16 + ll;
                float bv = fcb[col];
                int kt = col >> 6;
                int byteoff = (2 * (col & 63));
                #pragma unroll
                for (int r2 = 0; r2 < 4; r2++) {
                    int row = wrow * 16 + lg * 4 + r2;
                    *(unsigned short*)((char*)BufB + kt * 8192 + row * 128 + (byteoff ^ ((row & 7) << 4))) = f2b(acc[nf][r2] + bv);
                }
            }
            __syncthreads();
            // residual: BufB += x0b
            #pragma unroll
            for (int i = 0; i < 4; i++) {
                int s = tid + i * 512;
                int row = s >> 5;
                int kb = (s & 31) * 16;
                int kt = kb >> 7, within = kb & 127;
                int swz = within ^ ((row & 7) << 4);
                bf16x8* dst = (bf16x8*)((char*)BufB + kt * 8192 + row * 128 + swz);
                bf16x8 xv = *dst;
                bf16x8 rv = *(const bf16x8*)((const char*)x0b + (size_t)(m0 + row) * 512 + kb);
                bf16x8 res;
                #pragma unroll
                for (int jj = 0; jj < 8; jj++)
                    res[jj] = (short)f2b(b2f((unsigned short)xv[jj]) + b2f((unsigned short)rv[jj]));
                *dst = res;
            }
        } else if (phase == 1) {
            #pragma unroll
            for (int nf = 0; nf < 8; nf++) {
                int col = wcol * 128 + nf * 16 + ll;
                float bv = f1b[col];
                int kt = col >> 6;
                int byteoff = (2 * (col & 63));
                #pragma unroll
                for (int r2 = 0; r2 < 4; r2++) {
                    int row = wrow * 16 + lg * 4 + r2;
                    float v = acc[nf][r2] + bv;
                    v = 0.5f * v * (1.f + erff(v * 0.70710678118654752f));
                    *(unsigned short*)((char*)BufA + kt * 8192 + row * 128 + (byteoff ^ ((row & 7) << 4))) = f2b(v);
                }
            }
        } else {
            int bb = m0 >> 10;
            int chunk = ((m0 & 1023) >> 4) + wrow;
            #pragma unroll
            for (int nf = 0; nf < 8; nf++) {
                int col = wcol * 128 + nf * 16 + ll;
                float s_ = acc[nf][0] + acc[nf][1] + acc[nf][2] + acc[nf][3];
                s_ += __shfl_xor(s_, 16);
                s_ += __shfl_xor(s_, 32);
                s_ += 16.f * f2bv[col];
                if (lg == 0)
                    part[((size_t)bb * 64 + chunk) * 256 + col] = s_;
            }
        }
    }
}

// ---------------- fused pool stage 2 + MLP head (eval BatchNorm) ----------------
__global__ __launch_bounds__(128) void head2_kernel(const float* __restrict__ part,
                                                    const float* __restrict__ h1_w, const float* __restrict__ h1_b,
                                                    const float* __restrict__ g, const float* __restrict__ be,
                                                    const float* __restrict__ mu, const float* __restrict__ var,
                                                    const float* __restrict__ h2_w, const float* __restrict__ h2_b,
                                                    float* __restrict__ out) {
    int b = blockIdx.x, j = threadIdx.x;
    __shared__ float pl[256];
    __shared__ float red[128];
    float s0 = 0.f, s1 = 0.f;
    for (int ch = 0; ch < 64; ch++) {
        s0 += part[((size_t)b * 64 + ch) * 256 + j];
        s1 += part[((size_t)b * 64 + ch) * 256 + j + 128];
    }
    pl[j] = s0 * (1.f / 1024.f);
    pl[j + 128] = s1 * (1.f / 1024.f);
    __syncthreads();
    float s = 0.f;
    for (int d = 0; d < 256; d++) s = fmaf(pl[d], h1_w[j * 256 + d], s);
    s += h1_b[j];
    s = (s - mu[j]) / sqrtf(var[j] + 1e-5f) * g[j] + be[j];
    s = fmaxf(s, 0.f);
    red[j] = s * h2_w[j];
    __syncthreads();
    for (int off = 64; off; off >>= 1) {
        if (j < off) red[j] += red[j + off];
        __syncthreads();
    }
    if (j == 0) out[b] = red[0] + h2_b[0];
}

// ---------------- launch ----------------
extern "C" void kernel_launch(void* const* d_in, const int* in_sizes, int n_in,
                              void* d_out, int out_size, void* d_ws, size_t ws_size,
                              hipStream_t stream) {
    (void)in_sizes; (void)n_in; (void)out_size; (void)ws_size;
    const int*   ids    = (const int*)d_in[0];
    const int*   amask  = (const int*)d_in[1];
    const float* emb_W  = (const float*)d_in[2];
    const float* emb_b  = (const float*)d_in[3];
    const float* wq = (const float*)d_in[4],  *bq = (const float*)d_in[5];
    const float* wk = (const float*)d_in[6],  *bk = (const float*)d_in[7];
    const float* wv = (const float*)d_in[8],  *bv = (const float*)d_in[9];
    const float* fcw = (const float*)d_in[10], *fcb = (const float*)d_in[11];
    const float* f1w = (const float*)d_in[12], *f1b = (const float*)d_in[13];
    const float* f2w = (const float*)d_in[14], *f2b_ = (const float*)d_in[15];
    const float* h1w = (const float*)d_in[16], *h1b = (const float*)d_in[17];
    const float* bng = (const float*)d_in[18], *bnb = (const float*)d_in[19];
    const float* bnm = (const float*)d_in[20], *bnv = (const float*)d_in[21];
    const float* h2w = (const float*)d_in[22], *h2b = (const float*)d_in[23];
    float* out = (float*)d_out;
    float* ws = (float*)d_ws;

    // workspace layout (float units)
    const size_t O_PE   = 0;                        // 262,144
    const size_t O_EMBT = O_PE + 262144;            // 3,840,000 (bf16 30000x256)
    const size_t O_X0B  = O_EMBT + 3840000;         // 2,097,152
    const size_t O_Q    = O_X0B + 2097152;          // 2,097,152
    const size_t O_K    = O_Q + 2097152;            // 2,097,152
    const size_t O_V    = O_K + 2097152;            // 2,097,152
    const size_t O_ATT  = O_V + 2097152;            // 2,097,152
    const size_t O_WQKV = O_ATT + 2097152;          // 98,304 (768x256 shorts)
    const size_t O_WB3  = O_WQKV + 98304;           // 98,304
    const size_t O_B768 = O_WB3 + 98304;            // 768
    const size_t O_PART = O_B768 + 768;             // 262,144 (16x64x256 f32)
    const size_t O_SPAN = O_PART + 262144;

    float* pe   = ws + O_PE;
    unsigned short* embT = (unsigned short*)(ws + O_EMBT);
    unsigned short* x0b  = (unsigned short*)(ws + O_X0B);
    unsigned short* Qb   = (unsigned short*)(ws + O_Q);
    unsigned short* Kb   = (unsigned short*)(ws + O_K);
    unsigned short* Vt   = (unsigned short*)(ws + O_V);
    unsigned short* attb = (unsigned short*)(ws + O_ATT);
    unsigned short* wqkv = (unsigned short*)(ws + O_WQKV);
    unsigned short* wb3  = (unsigned short*)(ws + O_WB3);
    float* bias768 = ws + O_B768;
    float* part = ws + O_PART;
    int* spans  = (int*)(ws + O_SPAN);

    prep_kernel<<<1617 + 938 * 8, 256, 0, stream>>>(amask, spans, pe,
                                                    wq, wk, wv, bq, bk, bv, wqkv, bias768,
                                                    fcw, f1w, f2w, wb3,
                                                    emb_W, emb_b, embT);

    qkv_kernel<<<256, 512, 0, stream>>>(ids, embT, pe, wqkv, bias768, x0b, Qb, Kb, Vt);

    attn_coop<<<512, 512, 0, stream>>>(Qb, Kb, Vt, spans, attb);

    ffn_kernel<<<256, 512, 0, stream>>>(attb, x0b, wb3, fcb, f1b, f2b_, part);

    head2_kernel<<<BATCH, 128, 0, stream>>>(part, h1w, h1b, bng, bnb, bnm, bnv, h2w, h2b, out);
}